// Round 4
// baseline (10273.947 us; speedup 1.0000x reference)
//
#include <hip/hip_runtime.h>

// ---------------------------------------------------------------------------
// Masked LSTM, B=64 L=512 E=1024 H=1024, fp32 in/out, bf16 MFMA internally.
//
// Baseline strategy (round 1, resubmitted unchanged — GPU never acquired):
// MINIMAL workspace (~17.6 MB), no global_load_lds, no hipMemsetAsync —
// eliminates every crash suspect from round 0; measurable baseline.
//
// Math per step t: g = x_t @ Wx^T + h @ Wm^T + bx + bm  ==  [x_t | h] @ Wcat^T + bsum
//   Wcat bf16 [4096][2048], packed row r = c*4 + gate (gate order f,i,o,c),
//   cols [0,1024) = Wx, [1024,2048) = Wm.
// Step kernel: 256 blocks x 256 thr (4 waves). Block owns 4 hidden cols
// (16 packed rows). Wave = K-quarter (512 of K=2048). 16x16x32 bf16 MFMA,
// LDS reduce over K-quarters, fused gate activation + c/h update + outputs.
// ---------------------------------------------------------------------------

#define B_   64
#define L_   512
#define E_   1024
#define H_   1024

typedef __attribute__((ext_vector_type(8))) short bf16x8;
typedef __attribute__((ext_vector_type(4))) float f32x4;

#define MFMA16(a, b, c) __builtin_amdgcn_mfma_f32_16x16x32_bf16((a), (b), (c), 0, 0, 0)

__device__ __forceinline__ unsigned short f2b(float f) {  // fp32 -> bf16 RNE bits
  unsigned int u = __float_as_uint(f);
  u += 0x7fffu + ((u >> 16) & 1u);
  return (unsigned short)(u >> 16);
}

__device__ __forceinline__ bf16x8 cvt8(const float* p) {  // 8 fp32 -> bf16x8
  float4 v0 = *reinterpret_cast<const float4*>(p);
  float4 v1 = *reinterpret_cast<const float4*>(p + 4);
  bf16x8 r;
  r[0] = (short)f2b(v0.x); r[1] = (short)f2b(v0.y);
  r[2] = (short)f2b(v0.z); r[3] = (short)f2b(v0.w);
  r[4] = (short)f2b(v1.x); r[5] = (short)f2b(v1.y);
  r[6] = (short)f2b(v1.z); r[7] = (short)f2b(v1.w);
  return r;
}

__device__ __forceinline__ float sigmoidf_(float x) { return 1.0f / (1.0f + __expf(-x)); }
__device__ __forceinline__ float tanhf_(float x) { return 2.0f / (1.0f + __expf(-2.0f * x)) - 1.0f; }

// ---------------- packing -------------------------------------------------
// Wcat[4096][2048] bf16; row r = c*4+g; cols<1024 from W{g}x[c][:], else W{g}m[c][:]
__global__ __launch_bounds__(256) void pack_w(const float* __restrict__ fx, const float* __restrict__ ix,
                                              const float* __restrict__ ox, const float* __restrict__ cx,
                                              const float* __restrict__ fm, const float* __restrict__ im,
                                              const float* __restrict__ om, const float* __restrict__ cm,
                                              unsigned short* __restrict__ wcat) {
  int e = (blockIdx.x * 256 + threadIdx.x) * 4;   // 8,388,608 elements total
  int r = e >> 11;                                 // packed row [0,4096)
  int col = e & 2047;
  int c = r >> 2, g = r & 3;
  const float* src;
  if (col < 1024) src = (g == 0 ? fx : g == 1 ? ix : g == 2 ? ox : cx) + c * 1024 + col;
  else            src = (g == 0 ? fm : g == 1 ? im : g == 2 ? om : cm) + c * 1024 + (col - 1024);
  float4 v = *reinterpret_cast<const float4*>(src);
  ushort4 o;
  o.x = f2b(v.x); o.y = f2b(v.y); o.z = f2b(v.z); o.w = f2b(v.w);
  *reinterpret_cast<ushort4*>(wcat + e) = o;
}

__global__ __launch_bounds__(256) void pack_b(const float* __restrict__ bfx, const float* __restrict__ bix,
                                              const float* __restrict__ box, const float* __restrict__ bcx,
                                              const float* __restrict__ bfm, const float* __restrict__ bim,
                                              const float* __restrict__ bom, const float* __restrict__ bcm,
                                              float* __restrict__ bsum) {
  int i = blockIdx.x * 256 + threadIdx.x;  // 4096
  int c = i >> 2, g = i & 3;
  const float* px = g == 0 ? bfx : g == 1 ? bix : g == 2 ? box : bcx;
  const float* pm = g == 0 ? bfm : g == 1 ? bim : g == 2 ? bom : bcm;
  bsum[i] = px[c] + pm[c];
}

__global__ __launch_bounds__(256) void zero_state(float* __restrict__ hst, float* __restrict__ cst,
                                                  unsigned short* __restrict__ hbf0) {
  int i = blockIdx.x * 256 + threadIdx.x;  // 65536
  hst[i] = 0.0f;
  cst[i] = 0.0f;
  hbf0[i] = 0;
}

// ---------------- fused LSTM step -----------------------------------------
__global__ __launch_bounds__(256) void lstm_step(const float* __restrict__ x,            // [64][512][1024] fp32
                                                 const unsigned short* __restrict__ hbf, // [64][1024] bf16
                                                 const unsigned short* __restrict__ wcat,// [4096][2048] bf16
                                                 const float* __restrict__ bsum,         // [4096]
                                                 const int* __restrict__ msk,            // [64][512]
                                                 float* __restrict__ hst,                // [64][1024] fp32
                                                 float* __restrict__ cst,                // [64][1024] fp32
                                                 unsigned short* __restrict__ hbf_out,   // [64][1024] bf16
                                                 float* __restrict__ out,                // [64][512][1024]
                                                 float* __restrict__ hT,                 // [64][1024]
                                                 float* __restrict__ cT,                 // [64][1024]
                                                 int t, int last) {
  __shared__ float gsh[4][64][17];                 // padded
  const int tid = threadIdx.x;
  const int kq = tid >> 6;                         // wave = K-quarter [0,4)
  const int lane = tid & 63;
  const int lr = lane & 15, lk = lane >> 4;
  const int c0 = blockIdx.x * 4;                   // hidden cols c0..c0+3
  const int r0 = blockIdx.x * 16;                  // packed W rows

  // B fragment: lane holds W[r0+lr][k..k+7] for k = kq*256 + lk*8 (+1024 for Wm half)
  const unsigned short* bp = wcat + (size_t)(r0 + lr) * 2048 + kq * 256 + lk * 8;

  f32x4 acc[4] = {};

  // ---- x half (K 0..1023, this wave's 256 slice), fp32 -> bf16 in regs ----
  const size_t xsb = (size_t)512 * 1024;           // floats per batch row
  const float* apx = x + ((size_t)lr * 512 + t) * 1024 + kq * 256 + lk * 8;
#pragma unroll
  for (int k = 0; k < 256; k += 32) {
    bf16x8 b = *reinterpret_cast<const bf16x8*>(bp + k);
    acc[0] = MFMA16(cvt8(apx + k), b, acc[0]);
    acc[1] = MFMA16(cvt8(apx + 16 * xsb + k), b, acc[1]);
    acc[2] = MFMA16(cvt8(apx + 32 * xsb + k), b, acc[2]);
    acc[3] = MFMA16(cvt8(apx + 48 * xsb + k), b, acc[3]);
  }

  // ---- h half (K 1024..2047 slice), bf16 direct ----
  const unsigned short* aph = hbf + lr * H_ + kq * 256 + lk * 8;
  const unsigned short* bph = bp + 1024;
#pragma unroll
  for (int k = 0; k < 256; k += 32) {
    bf16x8 b = *reinterpret_cast<const bf16x8*>(bph + k);
    acc[0] = MFMA16(*reinterpret_cast<const bf16x8*>(aph + k), b, acc[0]);
    acc[1] = MFMA16(*reinterpret_cast<const bf16x8*>(aph + 16 * H_ + k), b, acc[1]);
    acc[2] = MFMA16(*reinterpret_cast<const bf16x8*>(aph + 32 * H_ + k), b, acc[2]);
    acc[3] = MFMA16(*reinterpret_cast<const bf16x8*>(aph + 48 * H_ + k), b, acc[3]);
  }

  // partials -> LDS.  C/D layout: col=lane&15, row=(lane>>4)*4+j
#pragma unroll
  for (int mi = 0; mi < 4; ++mi)
#pragma unroll
    for (int j = 0; j < 4; ++j)
      gsh[kq][16 * mi + lk * 4 + j][lr] = acc[mi][j];
  __syncthreads();

  // ---- update: thread = (batch b, local col cc) ----
  const int b = tid >> 2, cc = tid & 3;
  float v[4];
#pragma unroll
  for (int g = 0; g < 4; ++g) {
    int rl = cc * 4 + g;
    v[g] = gsh[0][b][rl] + gsh[1][b][rl] + gsh[2][b][rl] + gsh[3][b][rl] + bsum[r0 + rl];
  }
  float f  = sigmoidf_(v[0]);
  float i_ = sigmoidf_(v[1]);
  float o_ = sigmoidf_(v[2]);
  float ct = tanhf_(v[3]);

  const int n = c0 + cc;
  const int si = b * H_ + n;
  float cold = cst[si];
  float cnew = f * cold + i_ * ct;                 // cell always updated
  cst[si] = cnew;
  float hx = o_ * tanhf_(cnew);
  float m = (float)msk[b * L_ + t];
  float hnew = hx * m + hst[si] * (1.0f - m);      // mask applies to hidden only
  hst[si] = hnew;
  hbf_out[si] = f2b(hnew);
  out[((size_t)b * L_ + t) * H_ + n] = hnew;
  if (last) { hT[si] = hnew; cT[si] = cnew; }
}

// ---------------- driver ---------------------------------------------------

extern "C" void kernel_launch(void* const* d_in, const int* in_sizes, int n_in,
                              void* d_out, int out_size, void* d_ws, size_t ws_size,
                              hipStream_t stream) {
  (void)in_sizes; (void)n_in; (void)out_size; (void)ws_size;

  // setup_inputs() dict order
  const float* x   = (const float*)d_in[0];
  const int*   msk = (const int*)d_in[1];
  const float* Wfx = (const float*)d_in[2];
  const float* bfx = (const float*)d_in[3];
  const float* Wfm = (const float*)d_in[4];
  const float* bfm = (const float*)d_in[5];
  const float* Wix = (const float*)d_in[6];
  const float* bix = (const float*)d_in[7];
  const float* Wim = (const float*)d_in[8];
  const float* bim = (const float*)d_in[9];
  const float* Wox = (const float*)d_in[10];
  const float* box = (const float*)d_in[11];
  const float* Wom = (const float*)d_in[12];
  const float* bom = (const float*)d_in[13];
  const float* Wcx = (const float*)d_in[14];
  const float* bcx = (const float*)d_in[15];
  const float* Wcm = (const float*)d_in[16];
  const float* bcm = (const float*)d_in[17];

  char* ws = (char*)d_ws;
  unsigned short* wcat = (unsigned short*)(ws + 0);            // 16,777,216 B
  float*          bsum = (float*)(ws + 16777216ull);           //     16,384 B
  float*          hst  = (float*)(ws + 16793600ull);           //    262,144 B
  float*          cst  = (float*)(ws + 17055744ull);           //    262,144 B
  unsigned short* hbf0 = (unsigned short*)(ws + 17317888ull);  //    131,072 B
  unsigned short* hbf1 = (unsigned short*)(ws + 17448960ull);  //    131,072 B
  // total: 17,580,032 B (~16.8 MB)

  pack_w<<<8192, 256, 0, stream>>>(Wfx, Wix, Wox, Wcx, Wfm, Wim, Wom, Wcm, wcat);
  pack_b<<<16, 256, 0, stream>>>(bfx, bix, box, bcx, bfm, bim, bom, bcm, bsum);
  zero_state<<<256, 256, 0, stream>>>(hst, cst, hbf0);

  float* out = (float*)d_out;
  float* hT = out + (size_t)B_ * L_ * H_;
  float* cT = hT + (size_t)B_ * H_;

  for (int t = 0; t < L_; ++t) {
    const unsigned short* hin = (t & 1) ? hbf1 : hbf0;
    unsigned short* hout = (t & 1) ? hbf0 : hbf1;
    lstm_step<<<256, 256, 0, stream>>>(x, hin, wcat, bsum, msk, hst, cst, hout,
                                       out, hT, cT, t, t == L_ - 1);
  }
}

// Round 5
// 5825.058 us; speedup vs baseline: 1.7638x; 1.7638x over previous
//
#include <hip/hip_runtime.h>

// ---------------------------------------------------------------------------
// Masked LSTM, B=64 L=512 E=1024 H=1024, fp32 in/out, bf16 MFMA internally.
//
// Round-5: hoist input projection out of the sequential loop.
//   xproj[b][t][4H] = x_t @ Wx^T + bx + bm   (chunked GEMM, T steps per chunk,
//                                             T chosen from ws_size)
//   step t: g = xproj_t + h @ Wm^T ; gates; c,h update; outputs.
// Step kernel: 256 blocks x 512 thr (8 waves = K-eighths of 1024).
// Packed row order r = c*4 + gate (f,i,o,c) everywhere (W, bsum, xproj cols).
// ---------------------------------------------------------------------------

#define B_   64
#define L_   512
#define E_   1024
#define H_   1024

typedef __attribute__((ext_vector_type(8))) short bf16x8;
typedef __attribute__((ext_vector_type(4))) float f32x4;

#define MFMA16(a, b, c) __builtin_amdgcn_mfma_f32_16x16x32_bf16((a), (b), (c), 0, 0, 0)

__device__ __forceinline__ unsigned short f2b(float f) {  // fp32 -> bf16 RNE bits
  unsigned int u = __float_as_uint(f);
  u += 0x7fffu + ((u >> 16) & 1u);
  return (unsigned short)(u >> 16);
}

__device__ __forceinline__ float sigmoidf_(float x) { return 1.0f / (1.0f + __expf(-x)); }
__device__ __forceinline__ float tanhf_(float x) { return 2.0f / (1.0f + __expf(-2.0f * x)) - 1.0f; }

// ---------------- packing -------------------------------------------------
// dst[4096][1024] bf16, row r = c*4+g from s{g}[c][:]
__global__ __launch_bounds__(256) void pack4(const float* __restrict__ s0, const float* __restrict__ s1,
                                             const float* __restrict__ s2, const float* __restrict__ s3,
                                             unsigned short* __restrict__ dst) {
  int e = (blockIdx.x * 256 + threadIdx.x) * 4;   // 4,194,304 elements
  int r = e >> 10, col = e & 1023;
  int c = r >> 2, g = r & 3;
  const float* s = g == 0 ? s0 : g == 1 ? s1 : g == 2 ? s2 : s3;
  float4 v = *reinterpret_cast<const float4*>(s + c * 1024 + col);
  ushort4 o;
  o.x = f2b(v.x); o.y = f2b(v.y); o.z = f2b(v.z); o.w = f2b(v.w);
  *reinterpret_cast<ushort4*>(dst + e) = o;
}

__global__ __launch_bounds__(256) void pack_bs(const float* __restrict__ bfx, const float* __restrict__ bix,
                                               const float* __restrict__ box, const float* __restrict__ bcx,
                                               const float* __restrict__ bfm, const float* __restrict__ bim,
                                               const float* __restrict__ bom, const float* __restrict__ bcm,
                                               float* __restrict__ bsum) {
  int i = blockIdx.x * 256 + threadIdx.x;  // 4096
  int c = i >> 2, g = i & 3;
  const float* px = g == 0 ? bfx : g == 1 ? bix : g == 2 ? box : bcx;
  const float* pm = g == 0 ? bfm : g == 1 ? bim : g == 2 ? bom : bcm;
  bsum[i] = px[c] + pm[c];
}

__global__ __launch_bounds__(256) void zero_state(float* __restrict__ hst, float* __restrict__ cst,
                                                  unsigned short* __restrict__ hbf0) {
  int i = blockIdx.x * 256 + threadIdx.x;  // 65536
  hst[i] = 0.0f;
  cst[i] = 0.0f;
  hbf0[i] = 0;
}

// ---------------- chunk GEMM: xproj = x@Wx^T + bsum -------------------------
// C[64*T][4096] fp32 = A[64*T][1024] @ B[4096][1024]^T, chunk row m = b*T+tl,
// A global row = b*512 + t0 + tl. 128x128 tile, BK=32, 4 waves 2x2,
// LDS stride 40 shorts (2-way conflicts only).
__global__ __launch_bounds__(256) void gemm_chunk(const float* __restrict__ x,
                                                  const unsigned short* __restrict__ wxp,
                                                  const float* __restrict__ bsum,
                                                  float* __restrict__ xproj,
                                                  int t0, int tshift) {
  __shared__ unsigned short As[128 * 40];
  __shared__ unsigned short Bs[128 * 40];
  const int tid = threadIdx.x;
  const int wave = tid >> 6, lane = tid & 63;
  const int lr = lane & 15, lk = lane >> 4;
  const int mt = blockIdx.x >> 5, nt = blockIdx.x & 31;
  const int m0 = mt * 128, n0 = nt * 128;
  const int wm = (wave >> 1) * 64, wn = (wave & 1) * 64;
  const int Tm1 = (1 << tshift) - 1;

  // staging map: thread -> (row = tid>>1, col half = (tid&1)*16)
  const int srow = tid >> 1, scol = (tid & 1) * 16;
  const int am = m0 + srow;
  const float* arow = x + ((size_t)(am >> tshift) * 512 + t0 + (am & Tm1)) * 1024 + scol;
  const unsigned short* brow = wxp + (size_t)(n0 + srow) * 1024 + scol;
  unsigned short* asd = As + srow * 40 + scol;
  unsigned short* bsd = Bs + srow * 40 + scol;

  f32x4 acc[4][4] = {};

  for (int k0 = 0; k0 < 1024; k0 += 32) {
    __syncthreads();
    // A: 16 fp32 -> 16 bf16
    float4 a0 = *reinterpret_cast<const float4*>(arow + k0);
    float4 a1 = *reinterpret_cast<const float4*>(arow + k0 + 4);
    float4 a2 = *reinterpret_cast<const float4*>(arow + k0 + 8);
    float4 a3 = *reinterpret_cast<const float4*>(arow + k0 + 12);
    bf16x8 av0, av1;
    av0[0] = (short)f2b(a0.x); av0[1] = (short)f2b(a0.y); av0[2] = (short)f2b(a0.z); av0[3] = (short)f2b(a0.w);
    av0[4] = (short)f2b(a1.x); av0[5] = (short)f2b(a1.y); av0[6] = (short)f2b(a1.z); av0[7] = (short)f2b(a1.w);
    av1[0] = (short)f2b(a2.x); av1[1] = (short)f2b(a2.y); av1[2] = (short)f2b(a2.z); av1[3] = (short)f2b(a2.w);
    av1[4] = (short)f2b(a3.x); av1[5] = (short)f2b(a3.y); av1[6] = (short)f2b(a3.z); av1[7] = (short)f2b(a3.w);
    *reinterpret_cast<bf16x8*>(asd) = av0;
    *reinterpret_cast<bf16x8*>(asd + 8) = av1;
    // B: bf16 direct
    *reinterpret_cast<bf16x8*>(bsd) = *reinterpret_cast<const bf16x8*>(brow + k0);
    *reinterpret_cast<bf16x8*>(bsd + 8) = *reinterpret_cast<const bf16x8*>(brow + k0 + 8);
    __syncthreads();

    bf16x8 avf[4], bvf[4];
#pragma unroll
    for (int i = 0; i < 4; ++i)
      avf[i] = *reinterpret_cast<const bf16x8*>(As + (wm + 16 * i + lr) * 40 + lk * 8);
#pragma unroll
    for (int i = 0; i < 4; ++i)
      bvf[i] = *reinterpret_cast<const bf16x8*>(Bs + (wn + 16 * i + lr) * 40 + lk * 8);
#pragma unroll
    for (int mi = 0; mi < 4; ++mi)
#pragma unroll
      for (int ni = 0; ni < 4; ++ni)
        acc[mi][ni] = MFMA16(avf[mi], bvf[ni], acc[mi][ni]);
  }

  // epilogue: col = lane&15 -> N, row = (lane>>4)*4+j -> M; add bias (bx+bm)
#pragma unroll
  for (int ni = 0; ni < 4; ++ni) {
    int gn = n0 + wn + 16 * ni + lr;
    float bias = bsum[gn];
#pragma unroll
    for (int mi = 0; mi < 4; ++mi) {
      int gm = m0 + wm + 16 * mi + lk * 4;
#pragma unroll
      for (int j = 0; j < 4; ++j)
        xproj[(size_t)(gm + j) * 4096 + gn] = acc[mi][ni][j] + bias;
    }
  }
}

// ---------------- fused LSTM step (h @ Wm^T only, K=1024) -------------------
// 256 blocks x 512 thr (8 waves = K-eighths). Block owns 4 hidden cols
// (16 packed rows). LDS reduce over 8 partials; fused update.
__global__ __launch_bounds__(512) void lstm_step(const unsigned short* __restrict__ hbf,
                                                 const unsigned short* __restrict__ wmp,
                                                 const float* __restrict__ xproj,   // chunk, row = b*T+tl
                                                 const int* __restrict__ msk,
                                                 float* __restrict__ hst,
                                                 float* __restrict__ cst,
                                                 unsigned short* __restrict__ hbf_out,
                                                 float* __restrict__ out,
                                                 float* __restrict__ hT,
                                                 float* __restrict__ cT,
                                                 int t, int tl, int T, int last) {
  __shared__ float gsh[8][64][20];                 // 40,960 B; stride 20 words -> 2-way max
  const int tid = threadIdx.x;
  const int kq = tid >> 6, lane = tid & 63;
  const int lr = lane & 15, lk = lane >> 4;
  const int c0 = blockIdx.x * 4;                   // hidden cols
  const int r0 = blockIdx.x * 16;                  // packed Wm rows

  // --- preload epilogue operands (latency hidden under MFMA phase) ---
  const int bb = tid >> 2, cc = tid & 3;
  float4 xq;
  float cold = 0.f, hold = 0.f, mval = 0.f;
  int si = 0;
  if (tid < 256) {
    xq = *reinterpret_cast<const float4*>(xproj + ((size_t)bb * T + tl) * 4096 + r0 + cc * 4);
    si = bb * H_ + c0 + cc;
    cold = cst[si];
    hold = hst[si];
    mval = (float)msk[bb * L_ + t];
  }

  // --- h @ Wm^T partial: this wave covers K slice [kq*128, kq*128+128) ---
  const unsigned short* ap = hbf + lr * H_ + kq * 128 + lk * 8;
  const unsigned short* bp = wmp + (size_t)(r0 + lr) * H_ + kq * 128 + lk * 8;

  f32x4 acc[4] = {};
#pragma unroll
  for (int k = 0; k < 128; k += 32) {
    bf16x8 b = *reinterpret_cast<const bf16x8*>(bp + k);
    acc[0] = MFMA16(*reinterpret_cast<const bf16x8*>(ap + k), b, acc[0]);
    acc[1] = MFMA16(*reinterpret_cast<const bf16x8*>(ap + 16 * H_ + k), b, acc[1]);
    acc[2] = MFMA16(*reinterpret_cast<const bf16x8*>(ap + 32 * H_ + k), b, acc[2]);
    acc[3] = MFMA16(*reinterpret_cast<const bf16x8*>(ap + 48 * H_ + k), b, acc[3]);
  }

  // partials -> LDS. C/D: col=lane&15 (W row), row=(lane>>4)*4+j (batch)
#pragma unroll
  for (int mi = 0; mi < 4; ++mi)
#pragma unroll
    for (int j = 0; j < 4; ++j)
      gsh[kq][16 * mi + lk * 4 + j][lr] = acc[mi][j];
  __syncthreads();

  if (tid < 256) {
    float vf = xq.x, vi = xq.y, vo = xq.z, vc = xq.w;
#pragma unroll
    for (int q = 0; q < 8; ++q) {
      float4 g4 = *reinterpret_cast<const float4*>(&gsh[q][bb][cc * 4]);
      vf += g4.x; vi += g4.y; vo += g4.z; vc += g4.w;
    }
    float f  = sigmoidf_(vf);
    float i_ = sigmoidf_(vi);
    float o_ = sigmoidf_(vo);
    float ct = tanhf_(vc);

    float cnew = f * cold + i_ * ct;               // cell always updated
    cst[si] = cnew;
    float hx = o_ * tanhf_(cnew);
    float hnew = hx * mval + hold * (1.0f - mval); // mask on hidden only
    hst[si] = hnew;
    hbf_out[si] = f2b(hnew);
    out[((size_t)bb * L_ + t) * H_ + c0 + cc] = hnew;
    if (last) { hT[si] = hnew; cT[si] = cnew; }
  }
}

// ---------------- driver ---------------------------------------------------

extern "C" void kernel_launch(void* const* d_in, const int* in_sizes, int n_in,
                              void* d_out, int out_size, void* d_ws, size_t ws_size,
                              hipStream_t stream) {
  (void)in_sizes; (void)n_in; (void)out_size;

  const float* x   = (const float*)d_in[0];
  const int*   msk = (const int*)d_in[1];
  const float* Wfx = (const float*)d_in[2];
  const float* bfx = (const float*)d_in[3];
  const float* Wfm = (const float*)d_in[4];
  const float* bfm = (const float*)d_in[5];
  const float* Wix = (const float*)d_in[6];
  const float* bix = (const float*)d_in[7];
  const float* Wim = (const float*)d_in[8];
  const float* bim = (const float*)d_in[9];
  const float* Wox = (const float*)d_in[10];
  const float* box = (const float*)d_in[11];
  const float* Wom = (const float*)d_in[12];
  const float* bom = (const float*)d_in[13];
  const float* Wcx = (const float*)d_in[14];
  const float* bcx = (const float*)d_in[15];
  const float* Wcm = (const float*)d_in[16];
  const float* bcm = (const float*)d_in[17];

  char* ws = (char*)d_ws;
  unsigned short* wxp  = (unsigned short*)(ws + 0);            //  8,388,608 B
  unsigned short* wmp  = (unsigned short*)(ws + 8388608ull);   //  8,388,608 B
  float*          bsum = (float*)(ws + 16777216ull);           //     16,384 B
  float*          hst  = (float*)(ws + 16793600ull);           //    262,144 B
  float*          cst  = (float*)(ws + 17055744ull);           //    262,144 B
  unsigned short* hbf0 = (unsigned short*)(ws + 17317888ull);  //    131,072 B
  unsigned short* hbf1 = (unsigned short*)(ws + 17448960ull);  //    131,072 B
  float*          xproj = (float*)(ws + 17580032ull);          //  T MB (chunk)

  // largest chunk T (power of 2, <=128) whose xproj fits the workspace
  int T = 128;
  while (T > 8 && 17580032ull + (size_t)T * 1048576ull > ws_size) T >>= 1;
  int tshift = (T == 128) ? 7 : (T == 64) ? 6 : (T == 32) ? 5 : (T == 16) ? 4 : 3;

  pack4<<<4096, 256, 0, stream>>>(Wfx, Wix, Wox, Wcx, wxp);
  pack4<<<4096, 256, 0, stream>>>(Wfm, Wim, Wom, Wcm, wmp);
  pack_bs<<<16, 256, 0, stream>>>(bfx, bix, box, bcx, bfm, bim, bom, bcm, bsum);
  zero_state<<<256, 256, 0, stream>>>(hst, cst, hbf0);

  float* out = (float*)d_out;
  float* hT = out + (size_t)B_ * L_ * H_;
  float* cT = hT + (size_t)B_ * H_;

  const int nchunks = 512 / T;
  for (int c = 0; c < nchunks; ++c) {
    const int t0 = c * T;
    gemm_chunk<<<(T / 2) * 32, 256, 0, stream>>>(x, wxp, bsum, xproj, t0, tshift);
    for (int tl = 0; tl < T; ++tl) {
      const int t = t0 + tl;
      const unsigned short* hin = (t & 1) ? hbf1 : hbf0;
      unsigned short* hout = (t & 1) ? hbf0 : hbf1;
      lstm_step<<<256, 512, 0, stream>>>(hin, wmp, xproj, msk, hst, cst, hout,
                                         out, hT, cT, t, tl, T, t == L_ - 1);
    }
  }
}